// Round 1
// baseline (653.872 us; speedup 1.0000x reference)
//
#include <hip/hip_runtime.h>
#include <math.h>

#define N_NODES 100000
#define N_EDGES 1600000
#define HIDDEN 128

// ---------------------------------------------------------------------------
// Kernel 0: zero the direction_units accumulator (lives inside d_out).
// ---------------------------------------------------------------------------
__global__ void zero_du_kernel(float* __restrict__ du, int n) {
    int i = blockIdx.x * blockDim.x + threadIdx.x;
    if (i < n) du[i] = 0.0f;
}

// ---------------------------------------------------------------------------
// Kernel 1: per-edge unit vector, scatter-add to both endpoints.
// ---------------------------------------------------------------------------
__global__ void edge_scatter_kernel(const float* __restrict__ pos,
                                    const int* __restrict__ eidx,
                                    float* __restrict__ du) {
    int e = blockIdx.x * blockDim.x + threadIdx.x;
    if (e >= N_EDGES) return;
    int r = eidx[e];
    int c = eidx[N_EDGES + e];

    float dx = pos[c * 3 + 0] - pos[r * 3 + 0];
    float dy = pos[c * 3 + 1] - pos[r * 3 + 1];
    float dz = pos[c * 3 + 2] - pos[r * 3 + 2];
    float dist = sqrtf(dx * dx + dy * dy + dz * dz) + 1e-8f;
    float inv = 1.0f / dist;
    float ux = dx * inv, uy = dy * inv, uz = dz * inv;

    atomicAdd(&du[r * 3 + 0],  ux);
    atomicAdd(&du[r * 3 + 1],  uy);
    atomicAdd(&du[r * 3 + 2],  uz);
    atomicAdd(&du[c * 3 + 0], -ux);
    atomicAdd(&du[c * 3 + 1], -uy);
    atomicAdd(&du[c * 3 + 2], -uz);
}

// ---------------------------------------------------------------------------
// Kernel 2: angular_info[n][:] = ||du[n]||^2, 32 lanes per node, float4 stores.
// Grid covers exactly N_NODES*32 threads (N_NODES*32 % 256 == 0).
// ---------------------------------------------------------------------------
__global__ void angular_kernel(const float* __restrict__ du,
                               float* __restrict__ ang) {
    int gid = blockIdx.x * blockDim.x + threadIdx.x;
    int node = gid >> 5;   // 32 lanes per node
    int c4   = gid & 31;   // which float4 of the 128-wide row
    float x = du[node * 3 + 0];
    float y = du[node * 3 + 1];
    float z = du[node * 3 + 2];
    float a = x * x + y * y + z * z;
    reinterpret_cast<float4*>(ang + (size_t)node * HIDDEN)[c4] =
        make_float4(a, a, a, a);
}

// ---------------------------------------------------------------------------
// Kernel 3: per-edge dihedral scalar -> broadcast 128-wide row.
// 256 edges per block; scalar computed once per edge, staged in LDS, then the
// whole block streams 256*128 floats with coalesced float4 stores.
// N_EDGES % 256 == 0, so no tail handling.
// ---------------------------------------------------------------------------
__global__ void dihedral_kernel(const float* __restrict__ pos,
                                const int* __restrict__ eidx,
                                const float* __restrict__ du,
                                float* __restrict__ dih) {
    __shared__ float vals[256];
    const int e0 = blockIdx.x * 256;
    const int e  = e0 + threadIdx.x;

    {
        int r = eidx[e];
        int c = eidx[N_EDGES + e];

        float dx = pos[c * 3 + 0] - pos[r * 3 + 0];
        float dy = pos[c * 3 + 1] - pos[r * 3 + 1];
        float dz = pos[c * 3 + 2] - pos[r * 3 + 2];
        float dist = sqrtf(dx * dx + dy * dy + dz * dz) + 1e-8f;
        float inv = 1.0f / dist;
        float ux = dx * inv, uy = dy * inv, uz = dz * inv;

        float vix = du[r * 3 + 0], viy = du[r * 3 + 1], viz = du[r * 3 + 2];
        float vjx = du[c * 3 + 0], vjy = du[c * 3 + 1], vjz = du[c * 3 + 2];

        // dot_vi = v_i . u ; dot_vj = v_j . (-u)
        float dvi = vix * ux + viy * uy + viz * uz;
        float dvj = -(vjx * ux + vjy * uy + vjz * uz);

        // w_ij = v_i - dvi * u ; w_ji = v_j - dvj * (-u) = v_j + dvj * u
        float wix = vix - dvi * ux;
        float wiy = viy - dvi * uy;
        float wiz = viz - dvi * uz;
        float wjx = vjx + dvj * ux;
        float wjy = vjy + dvj * uy;
        float wjz = vjz + dvj * uz;

        vals[threadIdx.x] = wix * wjx + wiy * wjy + wiz * wjz;
    }
    __syncthreads();

    // Fill 256 rows x 128 floats = 2048 float4 per 256-thread block (32/thread).
    float4* out = reinterpret_cast<float4*>(dih + (size_t)e0 * HIDDEN);
    #pragma unroll
    for (int it = 0; it < 32; ++it) {
        int i = it * 256 + threadIdx.x;   // 0 .. 8191
        float v = vals[i >> 5];           // broadcast within each 32-lane group
        out[i] = make_float4(v, v, v, v);
    }
}

// ---------------------------------------------------------------------------
extern "C" void kernel_launch(void* const* d_in, const int* in_sizes, int n_in,
                              void* d_out, int out_size, void* d_ws, size_t ws_size,
                              hipStream_t stream) {
    const float* pos  = (const float*)d_in[0];
    const int*   eidx = (const int*)d_in[1];
    // d_in[2] (vector_features) is unused by the reference math.

    float* out = (float*)d_out;
    float* ang = out;                                         // (N, 128)
    float* dih = out + (size_t)N_NODES * HIDDEN;              // (E, 128)
    float* du  = dih + (size_t)N_EDGES * HIDDEN;              // (N, 3)

    const int DU_ELEMS = N_NODES * 3;
    zero_du_kernel<<<(DU_ELEMS + 255) / 256, 256, 0, stream>>>(du, DU_ELEMS);

    edge_scatter_kernel<<<(N_EDGES + 255) / 256, 256, 0, stream>>>(pos, eidx, du);

    angular_kernel<<<(N_NODES * 32) / 256, 256, 0, stream>>>(du, ang);

    dihedral_kernel<<<N_EDGES / 256, 256, 0, stream>>>(pos, eidx, du, dih);
}

// Round 3
// 653.502 us; speedup vs baseline: 1.0006x; 1.0006x over previous
//
#include <hip/hip_runtime.h>
#include <math.h>

#define N_NODES 100000
#define N_EDGES 1600000
#define HIDDEN 128
#define DU_ELEMS (N_NODES * 3)

// Native 4-wide float vector (clang ext_vector_type) — required for
// __builtin_nontemporal_store; HIP's float4 class type is rejected.
typedef float vfloat4 __attribute__((ext_vector_type(4)));

// ---------------------------------------------------------------------------
// Kernel 0: zero the replicated accumulators (in d_ws).
// ---------------------------------------------------------------------------
__global__ void zero_acc_kernel(float* __restrict__ acc, int n) {
    int i = blockIdx.x * blockDim.x + threadIdx.x;
    if (i < n) acc[i] = 0.0f;
}

// ---------------------------------------------------------------------------
// Kernel 1: per-edge unit vector, scatter-add into replica (blockIdx & rmask).
// Replication divides same-line atomic contention by R.
// ---------------------------------------------------------------------------
__global__ void edge_scatter_kernel(const float* __restrict__ pos,
                                    const int* __restrict__ eidx,
                                    float* __restrict__ acc, int rmask) {
    int e = blockIdx.x * blockDim.x + threadIdx.x;
    if (e >= N_EDGES) return;
    float* du = acc + (size_t)(blockIdx.x & rmask) * DU_ELEMS;

    int r = eidx[e];
    int c = eidx[N_EDGES + e];

    float dx = pos[c * 3 + 0] - pos[r * 3 + 0];
    float dy = pos[c * 3 + 1] - pos[r * 3 + 1];
    float dz = pos[c * 3 + 2] - pos[r * 3 + 2];
    float dist = sqrtf(dx * dx + dy * dy + dz * dz) + 1e-8f;
    float inv = 1.0f / dist;
    float ux = dx * inv, uy = dy * inv, uz = dz * inv;

    atomicAdd(&du[r * 3 + 0],  ux);
    atomicAdd(&du[r * 3 + 1],  uy);
    atomicAdd(&du[r * 3 + 2],  uz);
    atomicAdd(&du[c * 3 + 0], -ux);
    atomicAdd(&du[c * 3 + 1], -uy);
    atomicAdd(&du[c * 3 + 2], -uz);
}

// ---------------------------------------------------------------------------
// Kernel 2: sum R replicas -> du (elementwise over N_NODES*3, coalesced).
// ---------------------------------------------------------------------------
__global__ void reduce_du_kernel(const float* __restrict__ acc,
                                 float* __restrict__ du, int R) {
    int i = blockIdx.x * blockDim.x + threadIdx.x;
    if (i >= DU_ELEMS) return;
    float s = 0.0f;
    for (int r = 0; r < R; ++r) s += acc[(size_t)r * DU_ELEMS + i];
    du[i] = s;
}

// ---------------------------------------------------------------------------
// Kernel 3: angular_info[n][:] = ||du[n]||^2, 32 lanes per node, float4 stores.
// ---------------------------------------------------------------------------
__global__ void angular_kernel(const float* __restrict__ du,
                               float* __restrict__ ang) {
    int gid = blockIdx.x * blockDim.x + threadIdx.x;
    int node = gid >> 5;
    int c4   = gid & 31;
    float x = du[node * 3 + 0];
    float y = du[node * 3 + 1];
    float z = du[node * 3 + 2];
    float a = x * x + y * y + z * z;
    vfloat4 v4 = {a, a, a, a};
    __builtin_nontemporal_store(v4,
        reinterpret_cast<vfloat4*>(ang + (size_t)node * HIDDEN) + c4);
}

// ---------------------------------------------------------------------------
// Kernel 4: per-edge dihedral scalar -> broadcast 128-wide row.
// Nontemporal float4 stores keep the 819 MB stream from evicting pos/du in L2.
// ---------------------------------------------------------------------------
__global__ void dihedral_kernel(const float* __restrict__ pos,
                                const int* __restrict__ eidx,
                                const float* __restrict__ du,
                                float* __restrict__ dih) {
    __shared__ float vals[256];
    const int e0 = blockIdx.x * 256;
    const int e  = e0 + threadIdx.x;

    {
        int r = eidx[e];
        int c = eidx[N_EDGES + e];

        float dx = pos[c * 3 + 0] - pos[r * 3 + 0];
        float dy = pos[c * 3 + 1] - pos[r * 3 + 1];
        float dz = pos[c * 3 + 2] - pos[r * 3 + 2];
        float dist = sqrtf(dx * dx + dy * dy + dz * dz) + 1e-8f;
        float inv = 1.0f / dist;
        float ux = dx * inv, uy = dy * inv, uz = dz * inv;

        float vix = du[r * 3 + 0], viy = du[r * 3 + 1], viz = du[r * 3 + 2];
        float vjx = du[c * 3 + 0], vjy = du[c * 3 + 1], vjz = du[c * 3 + 2];

        float dvi = vix * ux + viy * uy + viz * uz;
        float dvj = -(vjx * ux + vjy * uy + vjz * uz);

        float wix = vix - dvi * ux;
        float wiy = viy - dvi * uy;
        float wiz = viz - dvi * uz;
        float wjx = vjx + dvj * ux;
        float wjy = vjy + dvj * uy;
        float wjz = vjz + dvj * uz;

        vals[threadIdx.x] = wix * wjx + wiy * wjy + wiz * wjz;
    }
    __syncthreads();

    vfloat4* out = reinterpret_cast<vfloat4*>(dih + (size_t)e0 * HIDDEN);
    #pragma unroll
    for (int it = 0; it < 32; ++it) {
        int i = it * 256 + threadIdx.x;   // 0 .. 8191
        float v = vals[i >> 5];
        vfloat4 v4 = {v, v, v, v};
        __builtin_nontemporal_store(v4, out + i);
    }
}

// ---------------------------------------------------------------------------
extern "C" void kernel_launch(void* const* d_in, const int* in_sizes, int n_in,
                              void* d_out, int out_size, void* d_ws, size_t ws_size,
                              hipStream_t stream) {
    const float* pos  = (const float*)d_in[0];
    const int*   eidx = (const int*)d_in[1];

    float* out = (float*)d_out;
    float* ang = out;                                         // (N, 128)
    float* dih = out + (size_t)N_NODES * HIDDEN;              // (E, 128)
    float* du  = dih + (size_t)N_EDGES * HIDDEN;              // (N, 3)

    // Pick replication factor R (power of two, up to 16) that fits d_ws.
    const size_t duBytes = (size_t)DU_ELEMS * sizeof(float);
    int R = 0;
    if (ws_size >= duBytes) {
        R = 1;
        while (R * 2 <= 16 && (size_t)(R * 2) * duBytes <= ws_size) R *= 2;
    }
    float* acc = (R > 0) ? (float*)d_ws : du;   // fallback: accumulate in du
    int Reff = (R > 0) ? R : 1;

    const int accElems = Reff * DU_ELEMS;
    zero_acc_kernel<<<(accElems + 255) / 256, 256, 0, stream>>>(acc, accElems);

    edge_scatter_kernel<<<(N_EDGES + 255) / 256, 256, 0, stream>>>(
        pos, eidx, acc, Reff - 1);

    reduce_du_kernel<<<(DU_ELEMS + 255) / 256, 256, 0, stream>>>(acc, du, Reff);

    angular_kernel<<<(N_NODES * 32) / 256, 256, 0, stream>>>(du, ang);

    dihedral_kernel<<<N_EDGES / 256, 256, 0, stream>>>(pos, eidx, du, dih);
}